// Round 2
// baseline (548.840 us; speedup 1.0000x reference)
//
#include <hip/hip_runtime.h>

// ---------- constants ----------
#define BATCH 4
#define SEQ   2048
#define NHEAD 8
#define DQKV  64
#define DMODEL 512
#define ROWS  (BATCH*SEQ)          // 8192
#define BH    (BATCH*NHEAD)        // 32
#define HSTRIDE (SEQ*DQKV)         // 131072 elements per (b,h)

using f32x4  = __attribute__((ext_vector_type(4))) float;
using short8 = __attribute__((ext_vector_type(8))) short;
using short4v = __attribute__((ext_vector_type(4))) short;

__device__ inline short f2bf(float f) {
    unsigned u = __float_as_uint(f);
    u += 0x7FFFu + ((u >> 16) & 1u);
    return (short)(u >> 16);
}

// ---------- prep: layernorm q -> bf16 ----------
__global__ __launch_bounds__(256) void ln_cast_kernel(
        const float* __restrict__ q, const float* __restrict__ gamma,
        const float* __restrict__ beta, short* __restrict__ qn) {
    int wave = threadIdx.x >> 6;
    int lane = threadIdx.x & 63;
    int row  = blockIdx.x * 4 + wave;            // 8192 rows
    const float4* qr = (const float4*)(q + (size_t)row * DMODEL);
    float4 x0 = qr[lane * 2];
    float4 x1 = qr[lane * 2 + 1];
    float s  = x0.x + x0.y + x0.z + x0.w + x1.x + x1.y + x1.z + x1.w;
    float s2 = x0.x*x0.x + x0.y*x0.y + x0.z*x0.z + x0.w*x0.w
             + x1.x*x1.x + x1.y*x1.y + x1.z*x1.z + x1.w*x1.w;
    #pragma unroll
    for (int m = 1; m < 64; m <<= 1) {
        s  += __shfl_xor(s,  m);
        s2 += __shfl_xor(s2, m);
    }
    float mu  = s * (1.0f / DMODEL);
    float var = s2 * (1.0f / DMODEL) - mu * mu;
    float rstd = rsqrtf(var + 1e-6f);
    const float4* g = (const float4*)gamma;
    const float4* be = (const float4*)beta;
    float4 g0 = g[lane*2], g1 = g[lane*2+1];
    float4 b0 = be[lane*2], b1 = be[lane*2+1];
    short8 o;
    o[0] = f2bf((x0.x - mu) * rstd * g0.x + b0.x);
    o[1] = f2bf((x0.y - mu) * rstd * g0.y + b0.y);
    o[2] = f2bf((x0.z - mu) * rstd * g0.z + b0.z);
    o[3] = f2bf((x0.w - mu) * rstd * g0.w + b0.w);
    o[4] = f2bf((x1.x - mu) * rstd * g1.x + b1.x);
    o[5] = f2bf((x1.y - mu) * rstd * g1.y + b1.y);
    o[6] = f2bf((x1.z - mu) * rstd * g1.z + b1.z);
    o[7] = f2bf((x1.w - mu) * rstd * g1.w + b1.w);
    ((short8*)(qn + (size_t)row * DMODEL))[lane] = o;
}

// ---------- prep: k & v fp32 -> bf16 (one launch) ----------
__global__ __launch_bounds__(256) void cast_kv_kernel(
        const float* __restrict__ k, const float* __restrict__ v,
        short* __restrict__ kb, short* __restrict__ vb) {
    const float* src = blockIdx.y ? v : k;
    short* dst = blockIdx.y ? vb : kb;
    size_t i = ((size_t)blockIdx.x * 256 + threadIdx.x) * 8;
    float4 a = *(const float4*)(src + i);
    float4 b = *(const float4*)(src + i + 4);
    short8 o;
    o[0]=f2bf(a.x); o[1]=f2bf(a.y); o[2]=f2bf(a.z); o[3]=f2bf(a.w);
    o[4]=f2bf(b.x); o[5]=f2bf(b.y); o[6]=f2bf(b.z); o[7]=f2bf(b.w);
    *(short8*)(dst + i) = o;
}

// ---------- prep: tiled W[k][n] -> Wt[n][k] bf16, 4 weights ----------
__global__ __launch_bounds__(256) void castWT4_kernel(
        const float* __restrict__ W0, const float* __restrict__ W1,
        const float* __restrict__ W2, const float* __restrict__ W3,
        short* __restrict__ T0, short* __restrict__ T1,
        short* __restrict__ T2, short* __restrict__ T3) {
    __shared__ short tile[64 * 68];
    int w = blockIdx.z;
    const float* W = w==0 ? W0 : w==1 ? W1 : w==2 ? W2 : W3;
    short* T = w==0 ? T0 : w==1 ? T1 : w==2 ? T2 : T3;
    int ti = blockIdx.x, tj = blockIdx.y;      // n-tile, k-tile
    int tid = threadIdx.x;
    #pragma unroll
    for (int p = 0; p < 4; ++p) {
        int idx = tid + p * 256;               // 0..1023
        int kl = idx >> 4, c4 = idx & 15;
        float4 f = *(const float4*)(W + (size_t)(tj*64 + kl) * DMODEL + ti*64 + c4*4);
        short4v s; s[0]=f2bf(f.x); s[1]=f2bf(f.y); s[2]=f2bf(f.z); s[3]=f2bf(f.w);
        *(short4v*)(tile + kl*68 + c4*4) = s;
    }
    __syncthreads();
    #pragma unroll
    for (int p = 0; p < 4; ++p) {
        int idx = tid + p * 256;
        int nl = idx >> 4, kseg = idx & 15;
        short4v s;
        #pragma unroll
        for (int i = 0; i < 4; ++i) s[i] = tile[(kseg*4 + i)*68 + nl];
        *(short4v*)(T + (size_t)(ti*64 + nl) * DMODEL + tj*64 + kseg*4) = s;
    }
}

// ---------- prep: mask -> bitmask via ballot ----------
__global__ __launch_bounds__(256) void maskbits_kernel(
        const int* __restrict__ mask, unsigned long long* __restrict__ mbits) {
    size_t gtid = (size_t)blockIdx.x * 256 + threadIdx.x;
    int m = mask[gtid];
    unsigned long long b = __ballot(m != 0);
    if ((threadIdx.x & 63) == 0) mbits[gtid >> 6] = b;
}

// ---------- fused QKV projection GEMM ----------
// A in {qn,kb,vb} by column block; Wt: [512][512] bf16 n-major; out [B][H][S][64]
__global__ __launch_bounds__(256) void proj_qkv_kernel(
        const short* __restrict__ qn, const short* __restrict__ kb,
        const short* __restrict__ vb,
        const short* __restrict__ Wqt, const short* __restrict__ Wkt,
        const short* __restrict__ Wvt,
        short* __restrict__ qh, short* __restrict__ kh, short* __restrict__ vh) {
    int cb3 = blockIdx.y * 64;
    int which = cb3 >> 9;
    int CBB = cb3 & 511;
    const short* A  = which==0 ? qn  : which==1 ? kb  : vb;
    const short* Wt = which==0 ? Wqt : which==1 ? Wkt : Wvt;
    short* outh     = which==0 ? qh  : which==1 ? kh  : vh;
    // Q gets 1/sqrt(64) * log2(e) folded in (attention uses exp2)
    float scale = which==0 ? 0.18033688f : 1.0f;

    int tid = threadIdx.x;
    int wave = tid >> 6, lane = tid & 63;
    int wr = wave >> 1, wc = wave & 1;
    int RB = blockIdx.x * 64 + wr * 32;
    int CB = CBB + wc * 32;
    int lm = lane & 15, lg = lane >> 4;
    f32x4 acc00{}, acc01{}, acc10{}, acc11{};
    const short8* Ar0 = (const short8*)(A + (size_t)(RB + lm) * DMODEL);
    const short8* Ar1 = (const short8*)(A + (size_t)(RB + 16 + lm) * DMODEL);
    const short8* Br0 = (const short8*)(Wt + (size_t)(CB + lm) * DMODEL);
    const short8* Br1 = (const short8*)(Wt + (size_t)(CB + 16 + lm) * DMODEL);
    #pragma unroll 4
    for (int kk = 0; kk < DMODEL; kk += 32) {
        int ko = (kk >> 3) + lg;
        short8 a0 = Ar0[ko], a1 = Ar1[ko];
        short8 b0 = Br0[ko], b1 = Br1[ko];
        acc00 = __builtin_amdgcn_mfma_f32_16x16x32_bf16(a0, b0, acc00, 0, 0, 0);
        acc01 = __builtin_amdgcn_mfma_f32_16x16x32_bf16(a0, b1, acc01, 0, 0, 0);
        acc10 = __builtin_amdgcn_mfma_f32_16x16x32_bf16(a1, b0, acc10, 0, 0, 0);
        acc11 = __builtin_amdgcn_mfma_f32_16x16x32_bf16(a1, b1, acc11, 0, 0, 0);
    }
    f32x4 accs[2][2] = {{acc00, acc01}, {acc10, acc11}};
    #pragma unroll
    for (int i = 0; i < 2; ++i) {
        #pragma unroll
        for (int j = 0; j < 2; ++j) {
            int n = CB + j * 16 + lm;
            int h = n >> 6, d = n & 63;
            #pragma unroll
            for (int r = 0; r < 4; ++r) {
                int m = RB + i * 16 + lg * 4 + r;
                int b = m >> 11, s = m & 2047;
                outh[(size_t)(b * NHEAD + h) * HSTRIDE + (size_t)s * DQKV + d] =
                    f2bf(accs[i][j][r] * scale);
            }
        }
    }
}

// ---------- prep: vh [B][H][S][64] -> vt [B][H][64][S] ----------
__global__ __launch_bounds__(256) void vtrans_kernel(
        const short* __restrict__ vh, short* __restrict__ vt) {
    __shared__ short t[64 * 68];
    int st = blockIdx.x, bh = blockIdx.y;
    int s0 = st * 64;
    int tid = threadIdx.x;
    const short* src = vh + (size_t)bh * HSTRIDE + (size_t)s0 * DQKV;
    #pragma unroll
    for (int p = 0; p < 2; ++p) {
        int idx = tid + p * 256;               // 0..511
        int sl = idx >> 3, seg = idx & 7;
        short8 val = *(const short8*)(src + (size_t)sl * DQKV + seg * 8);
        short4v lo = {val[0], val[1], val[2], val[3]};
        short4v hi = {val[4], val[5], val[6], val[7]};
        *(short4v*)(t + sl*68 + seg*8)     = lo;
        *(short4v*)(t + sl*68 + seg*8 + 4) = hi;
    }
    __syncthreads();
    short* dst = vt + (size_t)bh * HSTRIDE + s0;   // row d, stride SEQ
    #pragma unroll
    for (int p = 0; p < 2; ++p) {
        int idx = tid + p * 256;
        int d = idx >> 3, sseg = idx & 7;
        short8 o;
        #pragma unroll
        for (int i = 0; i < 8; ++i) o[i] = t[(sseg*8 + i)*68 + d];
        *(short8*)(dst + (size_t)d * SEQ + sseg * 8) = o;
    }
}

// ---------- flash attention, barrier-free ----------
// qh: [B][H][S][64] bf16 pre-scaled by log2e/8; kh: [B][H][S][64];
// vt: [B][H][64][S]; mbits: [B][S][32] uint64; oh: [B][H][S][64]
__global__ __launch_bounds__(256) void attn_kernel(
        const short* __restrict__ qh, const short* __restrict__ kh,
        const short* __restrict__ vt, const unsigned long long* __restrict__ mbits,
        short* __restrict__ oh) {
    __shared__ short Pl[4 * 16 * 72];
    int tid = threadIdx.x, wave = tid >> 6, lane = tid & 63;
    int lm = lane & 15, lg = lane >> 4;
    int qt = blockIdx.x, bh = blockIdx.y;
    int b = bh >> 3;
    int qbase = qt * 64 + wave * 16;

    const short* Kbase = kh + (size_t)bh * HSTRIDE;
    const short* Vtb   = vt + (size_t)bh * HSTRIDE;
    const short8* Qrow = (const short8*)(qh + (size_t)bh * HSTRIDE + (size_t)(qbase + lm) * DQKV);
    short8 aq0 = Qrow[lg];
    short8 aq1 = Qrow[lg + 4];

    const unsigned long long* mb[4];
    #pragma unroll
    for (int r = 0; r < 4; ++r)
        mb[r] = mbits + ((size_t)(b * SEQ + qbase + lg * 4 + r) << 5);

    f32x4 o0{}, o1{}, o2{}, o3{};
    float rsum[4] = {0.f, 0.f, 0.f, 0.f};
    short* Pw = Pl + wave * 16 * 72;

    #pragma unroll 1
    for (int kt = 0; kt < SEQ; kt += 64) {
        // S = Q K^T, K B-fragments direct from global
        f32x4 sk[4];
        #pragma unroll
        for (int kg = 0; kg < 4; ++kg) {
            const short8* Kp = (const short8*)(Kbase + (size_t)(kt + kg * 16 + lm) * DQKV);
            short8 bk0 = Kp[lg], bk1 = Kp[lg + 4];
            f32x4 z{};
            z = __builtin_amdgcn_mfma_f32_16x16x32_bf16(aq0, bk0, z, 0, 0, 0);
            sk[kg] = __builtin_amdgcn_mfma_f32_16x16x32_bf16(aq1, bk1, z, 0, 0, 0);
        }

        // masked exp2 (log2e folded into Q scale), accumulate row sums, write P
        int w64 = kt >> 6;
        #pragma unroll
        for (int r = 0; r < 4; ++r) {
            unsigned long long msk = mb[r][w64] >> lm;
            #pragma unroll
            for (int kg = 0; kg < 4; ++kg) {
                float e = __builtin_amdgcn_exp2f(sk[kg][r]);
                float p = ((unsigned)(msk >> (kg * 16)) & 1u) ? e : 0.0f;
                rsum[r] += p;
                Pw[(lg * 4 + r) * 72 + kg * 16 + lm] = f2bf(p);
            }
        }

        // P round-trip is wave-private: no barrier needed
        short8 ap0 = *(const short8*)(Pw + lm * 72 + lg * 8);
        short8 ap1 = *(const short8*)(Pw + lm * 72 + 32 + lg * 8);

        // O += P V, V^T B-fragments direct from global
        {
            const short8* Vp = (const short8*)(Vtb + (size_t)(0 * 16 + lm) * SEQ + kt);
            o0 = __builtin_amdgcn_mfma_f32_16x16x32_bf16(ap0, Vp[lg], o0, 0, 0, 0);
            o0 = __builtin_amdgcn_mfma_f32_16x16x32_bf16(ap1, Vp[lg + 4], o0, 0, 0, 0);
        }
        {
            const short8* Vp = (const short8*)(Vtb + (size_t)(1 * 16 + lm) * SEQ + kt);
            o1 = __builtin_amdgcn_mfma_f32_16x16x32_bf16(ap0, Vp[lg], o1, 0, 0, 0);
            o1 = __builtin_amdgcn_mfma_f32_16x16x32_bf16(ap1, Vp[lg + 4], o1, 0, 0, 0);
        }
        {
            const short8* Vp = (const short8*)(Vtb + (size_t)(2 * 16 + lm) * SEQ + kt);
            o2 = __builtin_amdgcn_mfma_f32_16x16x32_bf16(ap0, Vp[lg], o2, 0, 0, 0);
            o2 = __builtin_amdgcn_mfma_f32_16x16x32_bf16(ap1, Vp[lg + 4], o2, 0, 0, 0);
        }
        {
            const short8* Vp = (const short8*)(Vtb + (size_t)(3 * 16 + lm) * SEQ + kt);
            o3 = __builtin_amdgcn_mfma_f32_16x16x32_bf16(ap0, Vp[lg], o3, 0, 0, 0);
            o3 = __builtin_amdgcn_mfma_f32_16x16x32_bf16(ap1, Vp[lg + 4], o3, 0, 0, 0);
        }
    }

    // single deferred row-sum reduction across the 16 lm lanes
    #pragma unroll
    for (int m = 1; m < 16; m <<= 1) {
        #pragma unroll
        for (int r = 0; r < 4; ++r) rsum[r] += __shfl_xor(rsum[r], m);
    }
    float rinv[4];
    #pragma unroll
    for (int r = 0; r < 4; ++r) rinv[r] = __builtin_amdgcn_rcpf(rsum[r]);

    short* obase = oh + (size_t)bh * HSTRIDE;
    f32x4 oo[4] = {o0, o1, o2, o3};
    #pragma unroll
    for (int dt = 0; dt < 4; ++dt) {
        #pragma unroll
        for (int r = 0; r < 4; ++r) {
            obase[(size_t)(qbase + lg * 4 + r) * DQKV + dt * 16 + lm] =
                f2bf(oo[dt][r] * rinv[r]);
        }
    }
}

// ---------- output projection + residual ----------
__global__ __launch_bounds__(256) void outproj_kernel(
        const short* __restrict__ Ah, const short* __restrict__ Wfct,
        const float* __restrict__ resid, float* __restrict__ out) {
    int tid = threadIdx.x;
    int wave = tid >> 6, lane = tid & 63;
    int wr = wave >> 1, wc = wave & 1;
    int RB = blockIdx.x * 64 + wr * 32;
    int CB = blockIdx.y * 64 + wc * 32;
    int lm = lane & 15, lg = lane >> 4;

    int m0 = RB + lm, m1 = RB + 16 + lm;
    size_t rb0 = (size_t)(m0 >> 11) * (NHEAD * HSTRIDE) + (size_t)(m0 & 2047) * DQKV;
    size_t rb1 = (size_t)(m1 >> 11) * (NHEAD * HSTRIDE) + (size_t)(m1 & 2047) * DQKV;
    const short8* Br0 = (const short8*)(Wfct + (size_t)(CB + lm) * DMODEL);
    const short8* Br1 = (const short8*)(Wfct + (size_t)(CB + 16 + lm) * DMODEL);

    f32x4 acc00{}, acc01{}, acc10{}, acc11{};
    #pragma unroll 4
    for (int kk = 0; kk < DMODEL; kk += 32) {
        int k = kk + lg * 8;
        size_t aoff = (size_t)(k >> 6) * HSTRIDE + (k & 63);
        short8 a0 = *(const short8*)(Ah + rb0 + aoff);
        short8 a1 = *(const short8*)(Ah + rb1 + aoff);
        int ko = (kk >> 3) + lg;
        short8 b0 = Br0[ko], b1 = Br1[ko];
        acc00 = __builtin_amdgcn_mfma_f32_16x16x32_bf16(a0, b0, acc00, 0, 0, 0);
        acc01 = __builtin_amdgcn_mfma_f32_16x16x32_bf16(a0, b1, acc01, 0, 0, 0);
        acc10 = __builtin_amdgcn_mfma_f32_16x16x32_bf16(a1, b0, acc10, 0, 0, 0);
        acc11 = __builtin_amdgcn_mfma_f32_16x16x32_bf16(a1, b1, acc11, 0, 0, 0);
    }
    f32x4 accs[2][2] = {{acc00, acc01}, {acc10, acc11}};
    #pragma unroll
    for (int i = 0; i < 2; ++i) {
        #pragma unroll
        for (int j = 0; j < 2; ++j) {
            int n = CB + j * 16 + lm;
            #pragma unroll
            for (int r = 0; r < 4; ++r) {
                int m = RB + i * 16 + lg * 4 + r;
                size_t idx = (size_t)m * DMODEL + n;
                out[idx] = accs[i][j][r] + resid[idx];
            }
        }
    }
}

// ---------- host launch ----------
extern "C" void kernel_launch(void* const* d_in, const int* in_sizes, int n_in,
                              void* d_out, int out_size, void* d_ws, size_t ws_size,
                              hipStream_t stream) {
    const float* q     = (const float*)d_in[0];
    const float* k     = (const float*)d_in[1];
    const float* v     = (const float*)d_in[2];
    const int*   mask  = (const int*)d_in[3];
    const float* Wq    = (const float*)d_in[4];
    const float* Wk    = (const float*)d_in[5];
    const float* Wv    = (const float*)d_in[6];
    const float* Wfc   = (const float*)d_in[7];
    const float* gamma = (const float*)d_in[8];
    const float* beta  = (const float*)d_in[9];
    float* out = (float*)d_out;

    char* ws = (char*)d_ws;
    const size_t SZ_ROWS = (size_t)ROWS * DMODEL * sizeof(short);   // 8 MB
    const size_t SZ_W    = (size_t)DMODEL * DMODEL * sizeof(short); // 512 KB
    short* qn   = (short*)(ws);
    short* kbf  = (short*)(ws + SZ_ROWS);
    short* vbf  = (short*)(ws + 2 * SZ_ROWS);
    short* Wqt  = (short*)(ws + 3 * SZ_ROWS);
    short* Wkt  = (short*)(ws + 3 * SZ_ROWS + SZ_W);
    short* Wvt  = (short*)(ws + 3 * SZ_ROWS + 2 * SZ_W);
    short* Wfct = (short*)(ws + 3 * SZ_ROWS + 3 * SZ_W);
    short* qhb  = (short*)(ws + 3 * SZ_ROWS + 4 * SZ_W);
    short* khb  = (short*)(ws + 4 * SZ_ROWS + 4 * SZ_W);
    short* vhb  = (short*)(ws + 5 * SZ_ROWS + 4 * SZ_W);
    unsigned long long* mbits = (unsigned long long*)(ws + 6 * SZ_ROWS + 4 * SZ_W); // 2 MB
    short* vtb  = kbf;   // kbf dead after proj
    short* aout = qn;    // qn dead after proj

    ln_cast_kernel<<<ROWS / 4, 256, 0, stream>>>(q, gamma, beta, qn);
    cast_kv_kernel<<<dim3(ROWS * DMODEL / (256 * 8), 2), 256, 0, stream>>>(k, v, kbf, vbf);
    castWT4_kernel<<<dim3(8, 8, 4), 256, 0, stream>>>(Wq, Wk, Wv, Wfc, Wqt, Wkt, Wvt, Wfct);
    maskbits_kernel<<<BATCH * SEQ * SEQ / 256, 256, 0, stream>>>(mask, mbits);

    proj_qkv_kernel<<<dim3(ROWS / 64, 24), 256, 0, stream>>>(
        qn, kbf, vbf, Wqt, Wkt, Wvt, qhb, khb, vhb);

    vtrans_kernel<<<dim3(SEQ / 64, BH), 256, 0, stream>>>(vhb, vtb);

    attn_kernel<<<dim3(SEQ / 64, BH), 256, 0, stream>>>(qhb, khb, vtb, mbits, aout);

    outproj_kernel<<<dim3(ROWS / 64, DMODEL / 64), 256, 0, stream>>>(aout, Wfct, q, out);
}

// Round 4
// 299.458 us; speedup vs baseline: 1.8328x; 1.8328x over previous
//
#include <hip/hip_runtime.h>

// ---------- constants ----------
#define BATCH 4
#define SEQ   2048
#define NHEAD 8
#define DQKV  64
#define DMODEL 512
#define ROWS  (BATCH*SEQ)          // 8192
#define BH    (BATCH*NHEAD)        // 32
#define HSTRIDE (SEQ*DQKV)         // 131072 elements per (b,h)

using f32x4  = __attribute__((ext_vector_type(4))) float;
using short8 = __attribute__((ext_vector_type(8))) short;
using short4v = __attribute__((ext_vector_type(4))) short;

#define MFMA16(a,b,c) __builtin_amdgcn_mfma_f32_16x16x32_bf16((a),(b),(c),0,0,0)

__device__ inline short f2bf(float f) {
    unsigned u = __float_as_uint(f);
    u += 0x7FFFu + ((u >> 16) & 1u);
    return (short)(u >> 16);
}

// ---------- prep: layernorm q -> bf16 ----------
__global__ __launch_bounds__(256) void ln_cast_kernel(
        const float* __restrict__ q, const float* __restrict__ gamma,
        const float* __restrict__ beta, short* __restrict__ qn) {
    int wave = threadIdx.x >> 6;
    int lane = threadIdx.x & 63;
    int row  = blockIdx.x * 4 + wave;            // 8192 rows
    const float4* qr = (const float4*)(q + (size_t)row * DMODEL);
    float4 x0 = qr[lane * 2];
    float4 x1 = qr[lane * 2 + 1];
    float s  = x0.x + x0.y + x0.z + x0.w + x1.x + x1.y + x1.z + x1.w;
    float s2 = x0.x*x0.x + x0.y*x0.y + x0.z*x0.z + x0.w*x0.w
             + x1.x*x1.x + x1.y*x1.y + x1.z*x1.z + x1.w*x1.w;
    #pragma unroll
    for (int m = 1; m < 64; m <<= 1) {
        s  += __shfl_xor(s,  m);
        s2 += __shfl_xor(s2, m);
    }
    float mu  = s * (1.0f / DMODEL);
    float var = s2 * (1.0f / DMODEL) - mu * mu;
    float rstd = rsqrtf(var + 1e-6f);
    const float4* g = (const float4*)gamma;
    const float4* be = (const float4*)beta;
    float4 g0 = g[lane*2], g1 = g[lane*2+1];
    float4 b0 = be[lane*2], b1 = be[lane*2+1];
    short8 o;
    o[0] = f2bf((x0.x - mu) * rstd * g0.x + b0.x);
    o[1] = f2bf((x0.y - mu) * rstd * g0.y + b0.y);
    o[2] = f2bf((x0.z - mu) * rstd * g0.z + b0.z);
    o[3] = f2bf((x0.w - mu) * rstd * g0.w + b0.w);
    o[4] = f2bf((x1.x - mu) * rstd * g1.x + b1.x);
    o[5] = f2bf((x1.y - mu) * rstd * g1.y + b1.y);
    o[6] = f2bf((x1.z - mu) * rstd * g1.z + b1.z);
    o[7] = f2bf((x1.w - mu) * rstd * g1.w + b1.w);
    ((short8*)(qn + (size_t)row * DMODEL))[lane] = o;
}

// ---------- prep: k & v fp32 -> bf16 (one launch) ----------
__global__ __launch_bounds__(256) void cast_kv_kernel(
        const float* __restrict__ k, const float* __restrict__ v,
        short* __restrict__ kb, short* __restrict__ vb) {
    const float* src = blockIdx.y ? v : k;
    short* dst = blockIdx.y ? vb : kb;
    size_t i = ((size_t)blockIdx.x * 256 + threadIdx.x) * 8;
    float4 a = *(const float4*)(src + i);
    float4 b = *(const float4*)(src + i + 4);
    short8 o;
    o[0]=f2bf(a.x); o[1]=f2bf(a.y); o[2]=f2bf(a.z); o[3]=f2bf(a.w);
    o[4]=f2bf(b.x); o[5]=f2bf(b.y); o[6]=f2bf(b.z); o[7]=f2bf(b.w);
    *(short8*)(dst + i) = o;
}

// ---------- prep: tiled W[k][n] -> Wt[n][k] bf16, 4 weights ----------
__global__ __launch_bounds__(256) void castWT4_kernel(
        const float* __restrict__ W0, const float* __restrict__ W1,
        const float* __restrict__ W2, const float* __restrict__ W3,
        short* __restrict__ T0, short* __restrict__ T1,
        short* __restrict__ T2, short* __restrict__ T3) {
    __shared__ short tile[64 * 68];
    int w = blockIdx.z;
    const float* W = w==0 ? W0 : w==1 ? W1 : w==2 ? W2 : W3;
    short* T = w==0 ? T0 : w==1 ? T1 : w==2 ? T2 : T3;
    int ti = blockIdx.x, tj = blockIdx.y;      // n-tile, k-tile
    int tid = threadIdx.x;
    #pragma unroll
    for (int p = 0; p < 4; ++p) {
        int idx = tid + p * 256;               // 0..1023
        int kl = idx >> 4, c4 = idx & 15;
        float4 f = *(const float4*)(W + (size_t)(tj*64 + kl) * DMODEL + ti*64 + c4*4);
        short4v s; s[0]=f2bf(f.x); s[1]=f2bf(f.y); s[2]=f2bf(f.z); s[3]=f2bf(f.w);
        *(short4v*)(tile + kl*68 + c4*4) = s;
    }
    __syncthreads();
    #pragma unroll
    for (int p = 0; p < 4; ++p) {
        int idx = tid + p * 256;
        int nl = idx >> 4, kseg = idx & 15;
        short4v s;
        #pragma unroll
        for (int i = 0; i < 4; ++i) s[i] = tile[(kseg*4 + i)*68 + nl];
        *(short4v*)(T + (size_t)(ti*64 + nl) * DMODEL + tj*64 + kseg*4) = s;
    }
}

// ---------- prep: mask -> bitmask via ballot ----------
__global__ __launch_bounds__(256) void maskbits_kernel(
        const int* __restrict__ mask, unsigned long long* __restrict__ mbits) {
    size_t gtid = (size_t)blockIdx.x * 256 + threadIdx.x;
    int m = mask[gtid];
    unsigned long long b = __ballot(m != 0);
    if ((threadIdx.x & 63) == 0) mbits[gtid >> 6] = b;
}

// ---------- fused QKV projection GEMM: 128x64 tiles, LDS-dbuf W ----------
__global__ __launch_bounds__(256, 4) void proj_qkv_kernel(
        const short* __restrict__ qn, const short* __restrict__ kb,
        const short* __restrict__ vb,
        const short* __restrict__ Wqt, const short* __restrict__ Wkt,
        const short* __restrict__ Wvt,
        short* __restrict__ qhp, short* __restrict__ khp, short* __restrict__ vhp) {
    __shared__ short Wl[2 * 64 * 72];
    int tid = threadIdx.x, wave = tid >> 6, lane = tid & 63;
    int lm = lane & 15, lg = lane >> 4;
    int which = blockIdx.y >> 3;
    int CB0 = (blockIdx.y & 7) * 64;
    const short* A  = which==0 ? qn  : which==1 ? kb  : vb;
    const short* Wt = which==0 ? Wqt : which==1 ? Wkt : Wvt;
    short* outh     = which==0 ? qhp : which==1 ? khp : vhp;
    // Q gets 1/sqrt(64) * log2(e) folded in (attention uses exp2)
    float scale = which==0 ? 0.18033688f : 1.0f;

    int RBw = blockIdx.x * 128 + wave * 32;
    int scol = tid >> 2, sseg = tid & 3;
    const short* Wrow = Wt + (size_t)(CB0 + scol) * DMODEL;
    const short* Arow0 = A + (size_t)(RBw + lm) * DMODEL;
    const short* Arow1 = A + (size_t)(RBw + 16 + lm) * DMODEL;

    // prologue: A frags k0..63 + W chunk 0
    short8 a[2][2];
    a[0][0] = *(const short8*)(Arow0 + lg * 8);
    a[0][1] = *(const short8*)(Arow0 + 32 + lg * 8);
    a[1][0] = *(const short8*)(Arow1 + lg * 8);
    a[1][1] = *(const short8*)(Arow1 + 32 + lg * 8);
    {
        short8 w0 = ((const short8*)Wrow)[sseg], w1 = ((const short8*)Wrow)[sseg + 4];
        short8* wd = (short8*)(Wl + scol * 72);
        wd[sseg] = w0; wd[sseg + 4] = w1;
    }
    __syncthreads();

    f32x4 acc[2][4] = {};
    for (int kk = 0; kk < DMODEL; kk += 64) {
        int cur = (kk >> 6) & 1;
        bool more = (kk + 64) < DMODEL;
        short8 an[2][2], w0n, w1n;
        if (more) {
            an[0][0] = *(const short8*)(Arow0 + kk + 64 + lg * 8);
            an[0][1] = *(const short8*)(Arow0 + kk + 96 + lg * 8);
            an[1][0] = *(const short8*)(Arow1 + kk + 64 + lg * 8);
            an[1][1] = *(const short8*)(Arow1 + kk + 96 + lg * 8);
            w0n = ((const short8*)(Wrow + kk + 64))[sseg];
            w1n = ((const short8*)(Wrow + kk + 64))[sseg + 4];
        }
        const short* Wc = Wl + cur * 4608;
        #pragma unroll
        for (int cg = 0; cg < 4; ++cg) {
            short8 b0 = *(const short8*)(Wc + (cg*16 + lm) * 72 + lg * 8);
            short8 b1 = *(const short8*)(Wc + (cg*16 + lm) * 72 + 32 + lg * 8);
            #pragma unroll
            for (int rg = 0; rg < 2; ++rg) {
                acc[rg][cg] = MFMA16(a[rg][0], b0, acc[rg][cg]);
                acc[rg][cg] = MFMA16(a[rg][1], b1, acc[rg][cg]);
            }
        }
        if (more) {
            #pragma unroll
            for (int rg = 0; rg < 2; ++rg) { a[rg][0] = an[rg][0]; a[rg][1] = an[rg][1]; }
            short8* wd = (short8*)(Wl + (cur ^ 1) * 4608 + scol * 72);
            wd[sseg] = w0n; wd[sseg + 4] = w1n;
        }
        __syncthreads();
    }

    #pragma unroll
    for (int rg = 0; rg < 2; ++rg) {
        #pragma unroll
        for (int cg = 0; cg < 4; ++cg) {
            int n = CB0 + cg * 16 + lm;
            int h = n >> 6, d = n & 63;
            #pragma unroll
            for (int r = 0; r < 4; ++r) {
                int m = RBw + rg * 16 + lg * 4 + r;
                int bb = m >> 11, s = m & 2047;
                outh[(size_t)(bb * NHEAD + h) * HSTRIDE + (size_t)s * DQKV + d] =
                    f2bf(acc[rg][cg][r] * scale);
            }
        }
    }
}

// ---------- prep: vh [B][H][S][64] -> vt [B][H][64][S] ----------
__global__ __launch_bounds__(256) void vtrans_kernel(
        const short* __restrict__ vh, short* __restrict__ vt) {
    __shared__ short t[64 * 68];
    int st = blockIdx.x, bh = blockIdx.y;
    int s0 = st * 64;
    int tid = threadIdx.x;
    const short* src = vh + (size_t)bh * HSTRIDE + (size_t)s0 * DQKV;
    #pragma unroll
    for (int p = 0; p < 2; ++p) {
        int idx = tid + p * 256;               // 0..511
        int sl = idx >> 3, seg = idx & 7;
        short8 val = *(const short8*)(src + (size_t)sl * DQKV + seg * 8);
        short4v lo = {val[0], val[1], val[2], val[3]};
        short4v hi = {val[4], val[5], val[6], val[7]};
        *(short4v*)(t + sl*68 + seg*8)     = lo;
        *(short4v*)(t + sl*68 + seg*8 + 4) = hi;
    }
    __syncthreads();
    short* dst = vt + (size_t)bh * HSTRIDE + s0;   // row d, stride SEQ
    #pragma unroll
    for (int p = 0; p < 2; ++p) {
        int idx = tid + p * 256;
        int d = idx >> 3, sseg = idx & 7;
        short8 o;
        #pragma unroll
        for (int i = 0; i < 8; ++i) o[i] = t[(sseg*8 + i)*68 + d];
        *(short8*)(dst + (size_t)d * SEQ + sseg * 8) = o;
    }
}

// ---------- flash attention: LDS-dbuf K/V^T, 32 q/wave, MFMA row-sums ----------
// qh: [B][H][S][64] bf16 pre-scaled by log2e/8; kh: [B][H][S][64];
// vt: [B][H][64][S]; mbits: [B][S][32] uint64; oh: [B][H][S][64]
// LDS layout (shorts): KL at 0 (+cur*4608), VL at 9216 (+cur*4680, 65th row = ones),
//                      PW at 18576 (+wave*2176, stride 68)
#define KL_OFF 0
#define VL_OFF 9216
#define PW_OFF 18576
__global__ __launch_bounds__(256, 3) void attn_kernel(
        const short* __restrict__ qh, const short* __restrict__ kh,
        const short* __restrict__ vt, const unsigned long long* __restrict__ mbits,
        short* __restrict__ oh) {
    __shared__ short lds[27280];   // 54560 B -> 3 blocks/CU
    int tid = threadIdx.x, wave = tid >> 6, lane = tid & 63;
    int lm = lane & 15, lg = lane >> 4;
    int qt = blockIdx.x, bh = blockIdx.y;
    int b = bh >> 3;
    int qbase = qt * 128 + wave * 32;
    short* Pw = lds + PW_OFF + wave * 2176;

    const short* Kbase = kh + (size_t)bh * HSTRIDE;
    const short* Vtb   = vt + (size_t)bh * HSTRIDE;

    // Q fragments: 2 rowgroups x 2 k-halves
    short8 aq[2][2];
    #pragma unroll
    for (int rg = 0; rg < 2; ++rg) {
        const short8* Qrow = (const short8*)(qh + (size_t)bh * HSTRIDE
                              + (size_t)(qbase + rg * 16 + lm) * DQKV);
        aq[rg][0] = Qrow[lg];
        aq[rg][1] = Qrow[lg + 4];
    }

    // ones-row init (row 64 of both V buffers)
    if (tid < 128) lds[VL_OFF + (tid >> 6) * 4680 + 64 * 72 + (tid & 63)] = (short)0x3F80;

    f32x4 o[2][4] = {};
    f32x4 ox[2] = {};

    int skey = tid >> 2, sseg = tid & 3;
    const unsigned long long* mb = mbits + ((size_t)(b * SEQ + qbase) << 5)
                                   + (size_t)lg * 128;

    // prologue: stage tile 0
    {
        const short8* Ks = (const short8*)(Kbase + (size_t)skey * DQKV);
        short8 k0 = Ks[sseg], k1 = Ks[sseg + 4];
        const short* Vs = Vtb + (size_t)skey * SEQ;
        short8 v0 = *(const short8*)(Vs + sseg * 8);
        short8 v1 = *(const short8*)(Vs + sseg * 8 + 32);
        short8* kd = (short8*)(lds + KL_OFF + skey * 72);
        kd[sseg] = k0; kd[sseg + 4] = k1;
        *(short8*)(lds + VL_OFF + skey * 72 + sseg * 8)      = v0;
        *(short8*)(lds + VL_OFF + skey * 72 + sseg * 8 + 32) = v1;
    }
    __syncthreads();

    for (int kt = 0; kt < SEQ; kt += 64) {
        int cur = (kt >> 6) & 1;
        bool more = (kt + 64) < SEQ;
        short8 nk0, nk1, nv0, nv1;
        if (more) {
            const short8* Ks = (const short8*)(Kbase + (size_t)(kt + 64 + skey) * DQKV);
            nk0 = Ks[sseg]; nk1 = Ks[sseg + 4];
            const short* Vs = Vtb + (size_t)skey * SEQ + kt + 64;
            nv0 = *(const short8*)(Vs + sseg * 8);
            nv1 = *(const short8*)(Vs + sseg * 8 + 32);
        }

        // ---- S = Q K^T ----
        const short* Kc = lds + KL_OFF + cur * 4608;
        f32x4 sk[2][4];
        #pragma unroll
        for (int kg = 0; kg < 4; ++kg) {
            short8 bk0 = *(const short8*)(Kc + (kg*16 + lm) * 72 + lg * 8);
            short8 bk1 = *(const short8*)(Kc + (kg*16 + lm) * 72 + 32 + lg * 8);
            #pragma unroll
            for (int rg = 0; rg < 2; ++rg) {
                f32x4 z{};
                z = MFMA16(aq[rg][0], bk0, z);
                sk[rg][kg] = MFMA16(aq[rg][1], bk1, z);
            }
        }

        // ---- masked exp2 -> P (truncated bf16; row-sums come from MFMA) ----
        int w64 = kt >> 6;
        #pragma unroll
        for (int rg = 0; rg < 2; ++rg) {
            #pragma unroll
            for (int r = 0; r < 4; ++r) {
                unsigned long long msk = mb[rg * 512 + r * 32 + w64] >> lm;
                short* pdst = Pw + (rg * 16 + lg * 4 + r) * 68 + lm;
                #pragma unroll
                for (int kg = 0; kg < 4; ++kg) {
                    float e = __builtin_amdgcn_exp2f(sk[rg][kg][r]);
                    float p = ((unsigned)(msk >> (kg * 16)) & 1u) ? e : 0.0f;
                    pdst[kg * 16] = (short)(__float_as_uint(p) >> 16);
                }
            }
        }

        // ---- P fragments (wave-private LDS round-trip, no barrier) ----
        short8 ap[2][2];
        #pragma unroll
        for (int rg = 0; rg < 2; ++rg) {
            const short* pr = Pw + (rg * 16 + lm) * 68;
            short4v l0 = *(const short4v*)(pr + lg * 8);
            short4v h0 = *(const short4v*)(pr + lg * 8 + 4);
            short4v l1 = *(const short4v*)(pr + 32 + lg * 8);
            short4v h1 = *(const short4v*)(pr + 32 + lg * 8 + 4);
            ap[rg][0] = __builtin_shufflevector(l0, h0, 0,1,2,3,4,5,6,7);
            ap[rg][1] = __builtin_shufflevector(l1, h1, 0,1,2,3,4,5,6,7);
        }

        // ---- O += P V ----
        const short* Vc = lds + VL_OFF + cur * 4680;
        #pragma unroll
        for (int dt = 0; dt < 4; ++dt) {
            short8 bv0 = *(const short8*)(Vc + (dt*16 + lm) * 72 + lg * 8);
            short8 bv1 = *(const short8*)(Vc + (dt*16 + lm) * 72 + 32 + lg * 8);
            #pragma unroll
            for (int rg = 0; rg < 2; ++rg) {
                o[rg][dt] = MFMA16(ap[rg][0], bv0, o[rg][dt]);
                o[rg][dt] = MFMA16(ap[rg][1], bv1, o[rg][dt]);
            }
        }
        // row-sums via ones-row (col 0 of ox = sum_k P; other cols unused)
        {
            short8 bx0 = *(const short8*)(Vc + (64 + lm) * 72 + lg * 8);
            short8 bx1 = *(const short8*)(Vc + (64 + lm) * 72 + 32 + lg * 8);
            #pragma unroll
            for (int rg = 0; rg < 2; ++rg) {
                ox[rg] = MFMA16(ap[rg][0], bx0, ox[rg]);
                ox[rg] = MFMA16(ap[rg][1], bx1, ox[rg]);
            }
        }

        if (more) {
            int nxt = cur ^ 1;
            short8* kd = (short8*)(lds + KL_OFF + nxt * 4608 + skey * 72);
            kd[sseg] = nk0; kd[sseg + 4] = nk1;
            *(short8*)(lds + VL_OFF + nxt * 4680 + skey * 72 + sseg * 8)      = nv0;
            *(short8*)(lds + VL_OFF + nxt * 4680 + skey * 72 + sseg * 8 + 32) = nv1;
        }
        __syncthreads();
    }

    // epilogue: normalize by row-sum (broadcast from lm==0 lane of each lg group)
    short* ob = oh + (size_t)bh * HSTRIDE;
    #pragma unroll
    for (int rg = 0; rg < 2; ++rg) {
        float rinv[4];
        #pragma unroll
        for (int r = 0; r < 4; ++r)
            rinv[r] = __builtin_amdgcn_rcpf(__shfl(ox[rg][r], lane & 48));
        #pragma unroll
        for (int dt = 0; dt < 4; ++dt) {
            #pragma unroll
            for (int r = 0; r < 4; ++r) {
                ob[(size_t)(qbase + rg * 16 + lg * 4 + r) * DQKV + dt * 16 + lm] =
                    f2bf(o[rg][dt][r] * rinv[r]);
            }
        }
    }
}

// ---------- output projection + residual: 128x64 tiles, LDS-dbuf W ----------
__global__ __launch_bounds__(256, 4) void outproj_kernel(
        const short* __restrict__ Ah, const short* __restrict__ Wfct,
        const float* __restrict__ resid, float* __restrict__ out) {
    __shared__ short Wl[2 * 64 * 72];
    int tid = threadIdx.x, wave = tid >> 6, lane = tid & 63;
    int lm = lane & 15, lg = lane >> 4;
    int CB0 = blockIdx.y * 64;
    int RBw = blockIdx.x * 128 + wave * 32;
    int scol = tid >> 2, sseg = tid & 3;
    const short* Wrow = Wfct + (size_t)(CB0 + scol) * DMODEL;

    size_t rb[2];
    #pragma unroll
    for (int rg = 0; rg < 2; ++rg) {
        int m = RBw + rg * 16 + lm;
        rb[rg] = (size_t)(m >> 11) * (NHEAD * HSTRIDE) + (size_t)(m & 2047) * DQKV;
    }

    short8 a[2][2];
    #pragma unroll
    for (int rg = 0; rg < 2; ++rg) {
        a[rg][0] = *(const short8*)(Ah + rb[rg] + lg * 8);
        a[rg][1] = *(const short8*)(Ah + rb[rg] + 32 + lg * 8);
    }
    {
        short8 w0 = ((const short8*)Wrow)[sseg], w1 = ((const short8*)Wrow)[sseg + 4];
        short8* wd = (short8*)(Wl + scol * 72);
        wd[sseg] = w0; wd[sseg + 4] = w1;
    }
    __syncthreads();

    f32x4 acc[2][4] = {};
    for (int kk = 0; kk < DMODEL; kk += 64) {
        int cur = (kk >> 6) & 1;
        bool more = (kk + 64) < DMODEL;
        short8 an[2][2], w0n, w1n;
        if (more) {
            size_t hoff = (size_t)((kk >> 6) + 1) * HSTRIDE;
            #pragma unroll
            for (int rg = 0; rg < 2; ++rg) {
                an[rg][0] = *(const short8*)(Ah + rb[rg] + hoff + lg * 8);
                an[rg][1] = *(const short8*)(Ah + rb[rg] + hoff + 32 + lg * 8);
            }
            w0n = ((const short8*)(Wrow + kk + 64))[sseg];
            w1n = ((const short8*)(Wrow + kk + 64))[sseg + 4];
        }
        const short* Wc = Wl + cur * 4608;
        #pragma unroll
        for (int cg = 0; cg < 4; ++cg) {
            short8 b0 = *(const short8*)(Wc + (cg*16 + lm) * 72 + lg * 8);
            short8 b1 = *(const short8*)(Wc + (cg*16 + lm) * 72 + 32 + lg * 8);
            #pragma unroll
            for (int rg = 0; rg < 2; ++rg) {
                acc[rg][cg] = MFMA16(a[rg][0], b0, acc[rg][cg]);
                acc[rg][cg] = MFMA16(a[rg][1], b1, acc[rg][cg]);
            }
        }
        if (more) {
            #pragma unroll
            for (int rg = 0; rg < 2; ++rg) { a[rg][0] = an[rg][0]; a[rg][1] = an[rg][1]; }
            short8* wd = (short8*)(Wl + (cur ^ 1) * 4608 + scol * 72);
            wd[sseg] = w0n; wd[sseg + 4] = w1n;
        }
        __syncthreads();
    }

    #pragma unroll
    for (int rg = 0; rg < 2; ++rg) {
        #pragma unroll
        for (int cg = 0; cg < 4; ++cg) {
            int n = CB0 + cg * 16 + lm;
            #pragma unroll
            for (int r = 0; r < 4; ++r) {
                int m = RBw + rg * 16 + lg * 4 + r;
                size_t idx = (size_t)m * DMODEL + n;
                out[idx] = acc[rg][cg][r] + resid[idx];
            }
        }
    }
}

// ---------- host launch ----------
extern "C" void kernel_launch(void* const* d_in, const int* in_sizes, int n_in,
                              void* d_out, int out_size, void* d_ws, size_t ws_size,
                              hipStream_t stream) {
    const float* q     = (const float*)d_in[0];
    const float* k     = (const float*)d_in[1];
    const float* v     = (const float*)d_in[2];
    const int*   mask  = (const int*)d_in[3];
    const float* Wq    = (const float*)d_in[4];
    const float* Wk    = (const float*)d_in[5];
    const float* Wv    = (const float*)d_in[6];
    const float* Wfc   = (const float*)d_in[7];
    const float* gamma = (const float*)d_in[8];
    const float* beta  = (const float*)d_in[9];
    float* out = (float*)d_out;

    char* ws = (char*)d_ws;
    const size_t SZ_ROWS = (size_t)ROWS * DMODEL * sizeof(short);   // 8 MB
    const size_t SZ_W    = (size_t)DMODEL * DMODEL * sizeof(short); // 512 KB
    short* qn   = (short*)(ws);
    short* kbf  = (short*)(ws + SZ_ROWS);
    short* vbf  = (short*)(ws + 2 * SZ_ROWS);
    short* Wqt  = (short*)(ws + 3 * SZ_ROWS);
    short* Wkt  = (short*)(ws + 3 * SZ_ROWS + SZ_W);
    short* Wvt  = (short*)(ws + 3 * SZ_ROWS + 2 * SZ_W);
    short* Wfct = (short*)(ws + 3 * SZ_ROWS + 3 * SZ_W);
    short* qhb  = (short*)(ws + 3 * SZ_ROWS + 4 * SZ_W);
    short* khb  = (short*)(ws + 4 * SZ_ROWS + 4 * SZ_W);
    short* vhb  = (short*)(ws + 5 * SZ_ROWS + 4 * SZ_W);
    unsigned long long* mbits = (unsigned long long*)(ws + 6 * SZ_ROWS + 4 * SZ_W); // 2 MB
    short* vtb  = kbf;   // kbf dead after proj
    short* aout = qn;    // qn dead after proj

    ln_cast_kernel<<<ROWS / 4, 256, 0, stream>>>(q, gamma, beta, qn);
    cast_kv_kernel<<<dim3(ROWS * DMODEL / (256 * 8), 2), 256, 0, stream>>>(k, v, kbf, vbf);
    castWT4_kernel<<<dim3(8, 8, 4), 256, 0, stream>>>(Wq, Wk, Wv, Wfc, Wqt, Wkt, Wvt, Wfct);
    maskbits_kernel<<<BATCH * SEQ * SEQ / 256, 256, 0, stream>>>(mask, mbits);

    proj_qkv_kernel<<<dim3(ROWS / 128, 24), 256, 0, stream>>>(
        qn, kbf, vbf, Wqt, Wkt, Wvt, qhb, khb, vhb);

    vtrans_kernel<<<dim3(SEQ / 64, BH), 256, 0, stream>>>(vhb, vtb);

    attn_kernel<<<dim3(SEQ / 128, BH), 256, 0, stream>>>(qhb, khb, vtb, mbits, aout);

    outproj_kernel<<<dim3(ROWS / 128, DMODEL / 64), 256, 0, stream>>>(aout, Wfct, q, out);
}

// Round 5
// 284.133 us; speedup vs baseline: 1.9316x; 1.0539x over previous
//
#include <hip/hip_runtime.h>

// ---------- constants ----------
#define BATCH 4
#define SEQ   2048
#define NHEAD 8
#define DQKV  64
#define DMODEL 512
#define ROWS  (BATCH*SEQ)          // 8192
#define BH    (BATCH*NHEAD)        // 32
#define HSTRIDE (SEQ*DQKV)         // 131072 elements per (b,h)

using f32x4  = __attribute__((ext_vector_type(4))) float;
using short8 = __attribute__((ext_vector_type(8))) short;
using short4v = __attribute__((ext_vector_type(4))) short;

#define MFMA16(a,b,c) __builtin_amdgcn_mfma_f32_16x16x32_bf16((a),(b),(c),0,0,0)

__device__ __forceinline__ short f2bf(float f) {
    unsigned u = __float_as_uint(f);
    u += 0x7FFFu + ((u >> 16) & 1u);
    return (short)(u >> 16);
}

// async global->LDS 16B DMA (per-lane gaddr; LDS dst must be waveBase + lane*16)
__device__ __forceinline__ void gl2lds16(const short* g, short* l) {
    __builtin_amdgcn_global_load_lds(
        (__attribute__((address_space(1))) void*)g,
        (__attribute__((address_space(3))) void*)l, 16, 0, 0);
}

// stage a 64-row x 64-short tile (8KB), XOR chunk-swizzled, via DMA.
// swizzle applied in GLOBAL source so LDS write order stays linear (lane*16).
__device__ __forceinline__ void stage64x64(const short* g0, int gstride, short* lt, int t) {
    #pragma unroll
    for (int p = 0; p < 2; ++p) {
        int o = p * 2048 + t * 8;          // shorts; per-lane 16B, linear
        int row = o >> 6;
        int c = ((o >> 3) & 7) ^ (row & 7);
        gl2lds16(g0 + (size_t)row * gstride + c * 8, lt + o);
    }
}

// read logical 16B chunk (row, c) from a swizzled 64-short-stride tile
__device__ __forceinline__ short8 trd(const short* t, int row, int c) {
    return *(const short8*)(t + row * 64 + ((c ^ (row & 7)) << 3));
}

// ---------- prep: LN(q) + cast k,v -> bf16 (one launch, grid.y = 0/1/2) ----------
__global__ __launch_bounds__(256) void prep_kernel(
        const float* __restrict__ q, const float* __restrict__ k,
        const float* __restrict__ v, const float* __restrict__ gamma,
        const float* __restrict__ beta,
        short* __restrict__ qn, short* __restrict__ kb, short* __restrict__ vb) {
    if (blockIdx.y == 0) {
        int wave = threadIdx.x >> 6, lane = threadIdx.x & 63;
        int row  = blockIdx.x * 4 + wave;
        const float4* qr = (const float4*)(q + (size_t)row * DMODEL);
        float4 x0 = qr[lane * 2];
        float4 x1 = qr[lane * 2 + 1];
        float s  = x0.x + x0.y + x0.z + x0.w + x1.x + x1.y + x1.z + x1.w;
        float s2 = x0.x*x0.x + x0.y*x0.y + x0.z*x0.z + x0.w*x0.w
                 + x1.x*x1.x + x1.y*x1.y + x1.z*x1.z + x1.w*x1.w;
        #pragma unroll
        for (int m = 1; m < 64; m <<= 1) {
            s  += __shfl_xor(s,  m);
            s2 += __shfl_xor(s2, m);
        }
        float mu  = s * (1.0f / DMODEL);
        float var = s2 * (1.0f / DMODEL) - mu * mu;
        float rstd = rsqrtf(var + 1e-6f);
        const float4* g = (const float4*)gamma;
        const float4* be = (const float4*)beta;
        float4 g0 = g[lane*2], g1 = g[lane*2+1];
        float4 b0 = be[lane*2], b1 = be[lane*2+1];
        short8 o;
        o[0] = f2bf((x0.x - mu) * rstd * g0.x + b0.x);
        o[1] = f2bf((x0.y - mu) * rstd * g0.y + b0.y);
        o[2] = f2bf((x0.z - mu) * rstd * g0.z + b0.z);
        o[3] = f2bf((x0.w - mu) * rstd * g0.w + b0.w);
        o[4] = f2bf((x1.x - mu) * rstd * g1.x + b1.x);
        o[5] = f2bf((x1.y - mu) * rstd * g1.y + b1.y);
        o[6] = f2bf((x1.z - mu) * rstd * g1.z + b1.z);
        o[7] = f2bf((x1.w - mu) * rstd * g1.w + b1.w);
        ((short8*)(qn + (size_t)row * DMODEL))[lane] = o;
    } else {
        const float* src = (blockIdx.y == 1) ? k : v;
        short* dst = (blockIdx.y == 1) ? kb : vb;
        size_t i = (size_t)blockIdx.x * 2048 + (size_t)threadIdx.x * 8;
        float4 a = *(const float4*)(src + i);
        float4 b = *(const float4*)(src + i + 4);
        short8 o;
        o[0]=f2bf(a.x); o[1]=f2bf(a.y); o[2]=f2bf(a.z); o[3]=f2bf(a.w);
        o[4]=f2bf(b.x); o[5]=f2bf(b.y); o[6]=f2bf(b.z); o[7]=f2bf(b.w);
        *(short8*)(dst + i) = o;
    }
}

// ---------- prep: tiled W[k][n] -> Wt[n][k] bf16, 4 weights ----------
__global__ __launch_bounds__(256) void castWT4_kernel(
        const float* __restrict__ W0, const float* __restrict__ W1,
        const float* __restrict__ W2, const float* __restrict__ W3,
        short* __restrict__ T0, short* __restrict__ T1,
        short* __restrict__ T2, short* __restrict__ T3) {
    __shared__ short tile[64 * 68];
    int w = blockIdx.z;
    const float* W = w==0 ? W0 : w==1 ? W1 : w==2 ? W2 : W3;
    short* T = w==0 ? T0 : w==1 ? T1 : w==2 ? T2 : T3;
    int ti = blockIdx.x, tj = blockIdx.y;
    int tid = threadIdx.x;
    #pragma unroll
    for (int p = 0; p < 4; ++p) {
        int idx = tid + p * 256;
        int kl = idx >> 4, c4 = idx & 15;
        float4 f = *(const float4*)(W + (size_t)(tj*64 + kl) * DMODEL + ti*64 + c4*4);
        short4v s; s[0]=f2bf(f.x); s[1]=f2bf(f.y); s[2]=f2bf(f.z); s[3]=f2bf(f.w);
        *(short4v*)(tile + kl*68 + c4*4) = s;
    }
    __syncthreads();
    #pragma unroll
    for (int p = 0; p < 4; ++p) {
        int idx = tid + p * 256;
        int nl = idx >> 4, kseg = idx & 15;
        short4v s;
        #pragma unroll
        for (int i = 0; i < 4; ++i) s[i] = tile[(kseg*4 + i)*68 + nl];
        *(short4v*)(T + (size_t)(ti*64 + nl) * DMODEL + tj*64 + kseg*4) = s;
    }
}

// ---------- prep: mask -> MFMA-lane-ordered bitmask words ----------
// word index = ((((b*64+qg)*32 + w64)*2 + rg)*4 + r)*4 + kg
// bit l (= 16*lg + lm) of word = mask[qg*32 + rg*16 + lg*4 + r][w64*64 + kg*16 + lm]
__global__ __launch_bounds__(256) void maskpack_kernel(
        const int* __restrict__ mask, unsigned long long* __restrict__ mp) {
    int gw = blockIdx.x * 4 + (threadIdx.x >> 6);
    int lane = threadIdx.x & 63;
    int r   = gw & 3;
    int rg  = (gw >> 2) & 1;
    int w64 = (gw >> 3) & 31;
    int qg  = (gw >> 8) & 63;
    int b   = gw >> 14;
    int row = qg * 32 + rg * 16 + (lane >> 4) * 4 + r;
    const int* src = mask + ((size_t)b * SEQ + row) * SEQ + w64 * 64 + (lane & 15);
    unsigned long long w0 = __ballot(src[0]  != 0);
    unsigned long long w1 = __ballot(src[16] != 0);
    unsigned long long w2 = __ballot(src[32] != 0);
    unsigned long long w3 = __ballot(src[48] != 0);
    if (lane == 0) {
        unsigned long long* d = mp + (size_t)gw * 4;
        d[0] = w0; d[1] = w1; d[2] = w2; d[3] = w3;
    }
}

// ---------- fused QKV projection: 128x64 tiles, DMA-swizzled W, V^T output ----------
__global__ __launch_bounds__(256, 4) void proj_qkv_kernel(
        const short* __restrict__ qn, const short* __restrict__ kb,
        const short* __restrict__ vb,
        const short* __restrict__ Wqt, const short* __restrict__ Wkt,
        const short* __restrict__ Wvt,
        short* __restrict__ qhp, short* __restrict__ khp, short* __restrict__ vtp) {
    __shared__ __align__(16) short Wl[2 * 4096];
    int tid = threadIdx.x, wave = tid >> 6, lane = tid & 63;
    int lm = lane & 15, lg = lane >> 4;
    int which = blockIdx.y >> 3;
    int CB0 = (blockIdx.y & 7) * 64;
    const short* A  = which==0 ? qn  : which==1 ? kb  : vb;
    const short* Wt = which==0 ? Wqt : which==1 ? Wkt : Wvt;
    // Q gets 1/sqrt(64) * log2(e) folded in (attention uses exp2)
    float scale = which==0 ? 0.18033688f : 1.0f;

    int RBw = blockIdx.x * 128 + wave * 32;
    const short* Arow0 = A + (size_t)(RBw + lm) * DMODEL;
    const short* Arow1 = A + (size_t)(RBw + 16 + lm) * DMODEL;
    const short* W0 = Wt + (size_t)CB0 * DMODEL;

    short8 a[2][2];
    a[0][0] = *(const short8*)(Arow0 + lg * 8);
    a[0][1] = *(const short8*)(Arow0 + 32 + lg * 8);
    a[1][0] = *(const short8*)(Arow1 + lg * 8);
    a[1][1] = *(const short8*)(Arow1 + 32 + lg * 8);
    stage64x64(W0, DMODEL, Wl, tid);
    __syncthreads();

    f32x4 acc[2][4] = {};
    for (int kk = 0; kk < DMODEL; kk += 64) {
        int cur = (kk >> 6) & 1;
        bool more = (kk + 64) < DMODEL;
        short8 an[2][2];
        if (more) {
            stage64x64(W0 + kk + 64, DMODEL, Wl + (cur ^ 1) * 4096, tid);
            an[0][0] = *(const short8*)(Arow0 + kk + 64 + lg * 8);
            an[0][1] = *(const short8*)(Arow0 + kk + 96 + lg * 8);
            an[1][0] = *(const short8*)(Arow1 + kk + 64 + lg * 8);
            an[1][1] = *(const short8*)(Arow1 + kk + 96 + lg * 8);
        }
        const short* Wc = Wl + cur * 4096;
        #pragma unroll
        for (int cg = 0; cg < 4; ++cg) {
            short8 b0 = trd(Wc, cg*16 + lm, lg);
            short8 b1 = trd(Wc, cg*16 + lm, lg + 4);
            #pragma unroll
            for (int rg = 0; rg < 2; ++rg) {
                acc[rg][cg] = MFMA16(a[rg][0], b0, acc[rg][cg]);
                acc[rg][cg] = MFMA16(a[rg][1], b1, acc[rg][cg]);
            }
        }
        if (more) {
            #pragma unroll
            for (int rg = 0; rg < 2; ++rg) { a[rg][0] = an[rg][0]; a[rg][1] = an[rg][1]; }
        }
        __syncthreads();
    }

    if (which < 2) {
        short* outh = which==0 ? qhp : khp;
        #pragma unroll
        for (int rg = 0; rg < 2; ++rg) {
            #pragma unroll
            for (int cg = 0; cg < 4; ++cg) {
                int n = CB0 + cg * 16 + lm;
                int h = n >> 6, d = n & 63;
                #pragma unroll
                for (int r = 0; r < 4; ++r) {
                    int m = RBw + rg * 16 + lg * 4 + r;
                    int bb = m >> 11, s = m & 2047;
                    outh[(size_t)(bb * NHEAD + h) * HSTRIDE + (size_t)s * DQKV + d] =
                        f2bf(acc[rg][cg][r] * scale);
                }
            }
        }
    } else {
        // V output transposed: vt[b][h][d][s], packed 4-wide along s
        int bb = RBw >> 11;
        #pragma unroll
        for (int rg = 0; rg < 2; ++rg) {
            int s0 = (RBw + rg * 16 + lg * 4) & 2047;
            #pragma unroll
            for (int cg = 0; cg < 4; ++cg) {
                int n = CB0 + cg * 16 + lm;
                int h = n >> 6, d = n & 63;
                short4v pk;
                #pragma unroll
                for (int r = 0; r < 4; ++r) pk[r] = f2bf(acc[rg][cg][r]);
                *(short4v*)(vtp + (size_t)(bb * NHEAD + h) * HSTRIDE
                            + (size_t)d * SEQ + s0) = pk;
            }
        }
    }
}

// ---------- flash attention: DMA-swizzled K/V^T dbuf, scalar-mask, const-ones rowsum ----------
// LDS (shorts): KL at 0 (+cur*4096), VL at 8192 (+cur*4096), PW at 16384 (+wave*2048)
__global__ __launch_bounds__(256, 2) void attn_kernel(
        const short* __restrict__ qh, const short* __restrict__ kh,
        const short* __restrict__ vt, const unsigned long long* __restrict__ mpack,
        short* __restrict__ oh) {
    __shared__ __align__(16) short lds[24576];   // 49152 B
    int tid = threadIdx.x, wave = tid >> 6, lane = tid & 63;
    int lm = lane & 15, lg = lane >> 4;
    int qt = blockIdx.x, bh = blockIdx.y, b = bh >> 3;
    int qbase = qt * 128 + wave * 32;
    short* Pw = lds + 16384 + wave * 2048;

    const short* Kbase = kh + (size_t)bh * HSTRIDE;
    const short* Vtb   = vt + (size_t)bh * HSTRIDE;

    short8 aq[2][2];
    #pragma unroll
    for (int rg = 0; rg < 2; ++rg) {
        const short8* Qrow = (const short8*)(qh + (size_t)bh * HSTRIDE
                              + (size_t)(qbase + rg * 16 + lm) * DQKV);
        aq[rg][0] = Qrow[lg];
        aq[rg][1] = Qrow[lg + 4];
    }

    // mask base: readfirstlane(qg) makes the address provably wave-uniform -> s_load
    int qg = __builtin_amdgcn_readfirstlane(qt * 4 + wave);
    const unsigned long long* mbase = mpack + (size_t)(b * 64 + qg) * 1024;

    const short one = (short)0x3F80;   // bf16 1.0
    short8 ones = {one, one, one, one, one, one, one, one};

    f32x4 o[2][4] = {};
    f32x4 ox[2] = {};

    // prologue: stage tile 0
    stage64x64(Kbase, DQKV, lds, tid);
    stage64x64(Vtb,   SEQ,  lds + 8192, tid);
    __syncthreads();

    for (int kt = 0; kt < SEQ; kt += 64) {
        int cur = (kt >> 6) & 1;
        if (kt + 64 < SEQ) {
            int nxt = cur ^ 1;
            stage64x64(Kbase + (size_t)(kt + 64) * DQKV, DQKV, lds + nxt * 4096, tid);
            stage64x64(Vtb + kt + 64, SEQ, lds + 8192 + nxt * 4096, tid);
        }
        const short* Kc = lds + cur * 4096;
        const short* Vc = lds + 8192 + cur * 4096;

        // ---- S = Q K^T ----
        f32x4 sk[2][4];
        #pragma unroll
        for (int kg = 0; kg < 4; ++kg) {
            short8 bk0 = trd(Kc, kg*16 + lm, lg);
            short8 bk1 = trd(Kc, kg*16 + lm, lg + 4);
            #pragma unroll
            for (int rg = 0; rg < 2; ++rg) {
                f32x4 z{};
                z = MFMA16(aq[rg][0], bk0, z);
                sk[rg][kg] = MFMA16(aq[rg][1], bk1, z);
            }
        }

        // ---- masked exp2 -> P (swizzled LDS tile); mask via SGPR-pair cndmask ----
        const unsigned long long* mw = mbase + (kt >> 6) * 32;
        #pragma unroll
        for (int rg = 0; rg < 2; ++rg) {
            #pragma unroll
            for (int r = 0; r < 4; ++r) {
                int row = rg * 16 + lg * 4 + r;
                short* pd = Pw + row * 64 + (lm & 7);
                #pragma unroll
                for (int kg = 0; kg < 4; ++kg) {
                    unsigned long long mword = mw[rg * 16 + r * 4 + kg];
                    float e = __builtin_amdgcn_exp2f(sk[rg][kg][r]);
                    float pe;
                    asm("v_cndmask_b32 %0, 0, %1, %2" : "=v"(pe) : "v"(e), "s"(mword));
                    int c = (2 * kg + (lm >> 3)) ^ (row & 7);
                    pd[c * 8] = (short)(__float_as_uint(pe) >> 16);
                }
            }
        }

        // ---- P fragments (wave-private; compiler inserts lgkm wait) ----
        short8 ap[2][2];
        #pragma unroll
        for (int rg = 0; rg < 2; ++rg) {
            ap[rg][0] = trd(Pw, rg*16 + lm, lg);
            ap[rg][1] = trd(Pw, rg*16 + lm, lg + 4);
        }

        // ---- O += P V ----
        #pragma unroll
        for (int dt = 0; dt < 4; ++dt) {
            short8 bv0 = trd(Vc, dt*16 + lm, lg);
            short8 bv1 = trd(Vc, dt*16 + lm, lg + 4);
            #pragma unroll
            for (int rg = 0; rg < 2; ++rg) {
                o[rg][dt] = MFMA16(ap[rg][0], bv0, o[rg][dt]);
                o[rg][dt] = MFMA16(ap[rg][1], bv1, o[rg][dt]);
            }
        }
        // rowsums via constant all-ones B fragment (every output col = rowsum)
        #pragma unroll
        for (int rg = 0; rg < 2; ++rg) {
            ox[rg] = MFMA16(ap[rg][0], ones, ox[rg]);
            ox[rg] = MFMA16(ap[rg][1], ones, ox[rg]);
        }
        __syncthreads();
    }

    // epilogue: normalize (own rowsum, no shuffle), store bf16
    short* ob = oh + (size_t)bh * HSTRIDE;
    #pragma unroll
    for (int rg = 0; rg < 2; ++rg) {
        float rinv[4];
        #pragma unroll
        for (int r = 0; r < 4; ++r) rinv[r] = __builtin_amdgcn_rcpf(ox[rg][r]);
        #pragma unroll
        for (int dt = 0; dt < 4; ++dt) {
            #pragma unroll
            for (int r = 0; r < 4; ++r) {
                ob[(size_t)(qbase + rg * 16 + lg * 4 + r) * DQKV + dt * 16 + lm] =
                    f2bf(o[rg][dt][r] * rinv[r]);
            }
        }
    }
}

// ---------- output projection + residual: DMA-swizzled W ----------
__global__ __launch_bounds__(256, 4) void outproj_kernel(
        const short* __restrict__ Ah, const short* __restrict__ Wfct,
        const float* __restrict__ resid, float* __restrict__ out) {
    __shared__ __align__(16) short Wl[2 * 4096];
    int tid = threadIdx.x, wave = tid >> 6, lane = tid & 63;
    int lm = lane & 15, lg = lane >> 4;
    int CB0 = blockIdx.y * 64;
    int RBw = blockIdx.x * 128 + wave * 32;
    const short* W0 = Wfct + (size_t)CB0 * DMODEL;

    size_t rb[2];
    #pragma unroll
    for (int rg = 0; rg < 2; ++rg) {
        int m = RBw + rg * 16 + lm;
        rb[rg] = (size_t)(m >> 11) * (NHEAD * HSTRIDE) + (size_t)(m & 2047) * DQKV;
    }

    short8 a[2][2];
    #pragma unroll
    for (int rg = 0; rg < 2; ++rg) {
        a[rg][0] = *(const short8*)(Ah + rb[rg] + lg * 8);
        a[rg][1] = *(const short8*)(Ah + rb[rg] + 32 + lg * 8);
    }
    stage64x64(W0, DMODEL, Wl, tid);
    __syncthreads();

    f32x4 acc[2][4] = {};
    for (int kk = 0; kk < DMODEL; kk += 64) {
        int cur = (kk >> 6) & 1;
        bool more = (kk + 64) < DMODEL;
        short8 an[2][2];
        if (more) {
            stage64x64(W0 + kk + 64, DMODEL, Wl + (cur ^ 1) * 4096, tid);
            size_t hoff = (size_t)((kk >> 6) + 1) * HSTRIDE;
            #pragma unroll
            for (int rg = 0; rg < 2; ++rg) {
                an[rg][0] = *(const short8*)(Ah + rb[rg] + hoff + lg * 8);
                an[rg][1] = *(const short8*)(Ah + rb[rg] + hoff + 32 + lg * 8);
            }
        }
        const short* Wc = Wl + cur * 4096;
        #pragma unroll
        for (int cg = 0; cg < 4; ++cg) {
            short8 b0 = trd(Wc, cg*16 + lm, lg);
            short8 b1 = trd(Wc, cg*16 + lm, lg + 4);
            #pragma unroll
            for (int rg = 0; rg < 2; ++rg) {
                acc[rg][cg] = MFMA16(a[rg][0], b0, acc[rg][cg]);
                acc[rg][cg] = MFMA16(a[rg][1], b1, acc[rg][cg]);
            }
        }
        if (more) {
            #pragma unroll
            for (int rg = 0; rg < 2; ++rg) { a[rg][0] = an[rg][0]; a[rg][1] = an[rg][1]; }
        }
        __syncthreads();
    }

    #pragma unroll
    for (int rg = 0; rg < 2; ++rg) {
        #pragma unroll
        for (int cg = 0; cg < 4; ++cg) {
            int n = CB0 + cg * 16 + lm;
            #pragma unroll
            for (int r = 0; r < 4; ++r) {
                int m = RBw + rg * 16 + lg * 4 + r;
                size_t idx = (size_t)m * DMODEL + n;
                out[idx] = acc[rg][cg][r] + resid[idx];
            }
        }
    }
}

// ---------- host launch ----------
extern "C" void kernel_launch(void* const* d_in, const int* in_sizes, int n_in,
                              void* d_out, int out_size, void* d_ws, size_t ws_size,
                              hipStream_t stream) {
    const float* q     = (const float*)d_in[0];
    const float* k     = (const float*)d_in[1];
    const float* v     = (const float*)d_in[2];
    const int*   mask  = (const int*)d_in[3];
    const float* Wq    = (const float*)d_in[4];
    const float* Wk    = (const float*)d_in[5];
    const float* Wv    = (const float*)d_in[6];
    const float* Wfc   = (const float*)d_in[7];
    const float* gamma = (const float*)d_in[8];
    const float* beta  = (const float*)d_in[9];
    float* out = (float*)d_out;

    char* ws = (char*)d_ws;
    const size_t SZ_ROWS = (size_t)ROWS * DMODEL * sizeof(short);   // 8 MB
    const size_t SZ_W    = (size_t)DMODEL * DMODEL * sizeof(short); // 512 KB
    short* qn   = (short*)(ws);
    short* kbf  = (short*)(ws + SZ_ROWS);
    short* vbf  = (short*)(ws + 2 * SZ_ROWS);
    short* Wqt  = (short*)(ws + 3 * SZ_ROWS);
    short* Wkt  = (short*)(ws + 3 * SZ_ROWS + SZ_W);
    short* Wvt  = (short*)(ws + 3 * SZ_ROWS + 2 * SZ_W);
    short* Wfct = (short*)(ws + 3 * SZ_ROWS + 3 * SZ_W);
    short* qhb  = (short*)(ws + 3 * SZ_ROWS + 4 * SZ_W);
    short* khb  = (short*)(ws + 4 * SZ_ROWS + 4 * SZ_W);
    short* vtb  = (short*)(ws + 5 * SZ_ROWS + 4 * SZ_W);
    unsigned long long* mpack = (unsigned long long*)(ws + 6 * SZ_ROWS + 4 * SZ_W); // 2 MB
    short* aout = qn;    // qn dead after proj

    prep_kernel<<<dim3(ROWS / 4, 3), 256, 0, stream>>>(q, k, v, gamma, beta, qn, kbf, vbf);
    castWT4_kernel<<<dim3(8, 8, 4), 256, 0, stream>>>(Wq, Wk, Wv, Wfc, Wqt, Wkt, Wvt, Wfct);
    maskpack_kernel<<<65536 / 4, 256, 0, stream>>>(mask, mpack);

    proj_qkv_kernel<<<dim3(ROWS / 128, 24), 256, 0, stream>>>(
        qn, kbf, vbf, Wqt, Wkt, Wvt, qhb, khb, vtb);

    attn_kernel<<<dim3(SEQ / 128, BH), 256, 0, stream>>>(qhb, khb, vtb, mpack, aout);

    outproj_kernel<<<dim3(ROWS / 128, DMODEL / 64), 256, 0, stream>>>(aout, Wfct, q, out);
}

// Round 6
// 261.855 us; speedup vs baseline: 2.0960x; 1.0851x over previous
//
#include <hip/hip_runtime.h>

// ---------- constants ----------
#define BATCH 4
#define SEQ   2048
#define NHEAD 8
#define DQKV  64
#define DMODEL 512
#define ROWS  (BATCH*SEQ)          // 8192
#define BH    (BATCH*NHEAD)        // 32
#define HSTRIDE (SEQ*DQKV)         // 131072 elements per (b,h)

using f32x4  = __attribute__((ext_vector_type(4))) float;
using short8 = __attribute__((ext_vector_type(8))) short;
using short4v = __attribute__((ext_vector_type(4))) short;

#define MFMA16(a,b,c) __builtin_amdgcn_mfma_f32_16x16x32_bf16((a),(b),(c),0,0,0)

__device__ __forceinline__ short f2bf(float f) {
    unsigned u = __float_as_uint(f);
    u += 0x7FFFu + ((u >> 16) & 1u);
    return (short)(u >> 16);
}

// async global->LDS 16B DMA (LDS dst = waveBase + lane*16)
__device__ __forceinline__ void gl2lds16(const short* g, short* l) {
    __builtin_amdgcn_global_load_lds(
        (__attribute__((address_space(1))) void*)g,
        (__attribute__((address_space(3))) void*)l, 16, 0, 0);
}

// stage a 64-row x 64-short tile (8KB), XOR chunk-swizzled, via DMA.
// swizzle applied in GLOBAL source so LDS write order stays linear.
__device__ __forceinline__ void stage64x64(const short* g0, int gstride, short* lt, int t) {
    #pragma unroll
    for (int p = 0; p < 2; ++p) {
        int o = p * 2048 + t * 8;          // shorts; per-lane 16B, linear
        int row = o >> 6;
        int c = ((o >> 3) & 7) ^ (row & 7);
        gl2lds16(g0 + (size_t)row * gstride + c * 8, lt + o);
    }
}
// 128-row variant (16KB)
__device__ __forceinline__ void stage128x64(const short* g0, int gstride, short* lt, int t) {
    stage64x64(g0, gstride, lt, t);
    stage64x64(g0 + (size_t)64 * gstride, gstride, lt + 4096, t);
}

// read logical 16B chunk (row, c) from a swizzled 64-short-stride tile
__device__ __forceinline__ short8 trd(const short* t, int row, int c) {
    return *(const short8*)(t + row * 64 + ((c ^ (row & 7)) << 3));
}

// ---------- prep: LN(q) + cast k,v -> bf16 (one launch, grid.y = 0/1/2) ----------
__global__ __launch_bounds__(256) void prep_kernel(
        const float* __restrict__ q, const float* __restrict__ k,
        const float* __restrict__ v, const float* __restrict__ gamma,
        const float* __restrict__ beta,
        short* __restrict__ qn, short* __restrict__ kb, short* __restrict__ vb) {
    if (blockIdx.y == 0) {
        int wave = threadIdx.x >> 6, lane = threadIdx.x & 63;
        int row  = blockIdx.x * 4 + wave;
        const float4* qr = (const float4*)(q + (size_t)row * DMODEL);
        float4 x0 = qr[lane * 2];
        float4 x1 = qr[lane * 2 + 1];
        float s  = x0.x + x0.y + x0.z + x0.w + x1.x + x1.y + x1.z + x1.w;
        float s2 = x0.x*x0.x + x0.y*x0.y + x0.z*x0.z + x0.w*x0.w
                 + x1.x*x1.x + x1.y*x1.y + x1.z*x1.z + x1.w*x1.w;
        #pragma unroll
        for (int m = 1; m < 64; m <<= 1) {
            s  += __shfl_xor(s,  m);
            s2 += __shfl_xor(s2, m);
        }
        float mu  = s * (1.0f / DMODEL);
        float var = s2 * (1.0f / DMODEL) - mu * mu;
        float rstd = rsqrtf(var + 1e-6f);
        const float4* g = (const float4*)gamma;
        const float4* be = (const float4*)beta;
        float4 g0 = g[lane*2], g1 = g[lane*2+1];
        float4 b0 = be[lane*2], b1 = be[lane*2+1];
        short8 o;
        o[0] = f2bf((x0.x - mu) * rstd * g0.x + b0.x);
        o[1] = f2bf((x0.y - mu) * rstd * g0.y + b0.y);
        o[2] = f2bf((x0.z - mu) * rstd * g0.z + b0.z);
        o[3] = f2bf((x0.w - mu) * rstd * g0.w + b0.w);
        o[4] = f2bf((x1.x - mu) * rstd * g1.x + b1.x);
        o[5] = f2bf((x1.y - mu) * rstd * g1.y + b1.y);
        o[6] = f2bf((x1.z - mu) * rstd * g1.z + b1.z);
        o[7] = f2bf((x1.w - mu) * rstd * g1.w + b1.w);
        ((short8*)(qn + (size_t)row * DMODEL))[lane] = o;
    } else {
        const float* src = (blockIdx.y == 1) ? k : v;
        short* dst = (blockIdx.y == 1) ? kb : vb;
        size_t i = (size_t)blockIdx.x * 2048 + (size_t)threadIdx.x * 8;
        float4 a = *(const float4*)(src + i);
        float4 b = *(const float4*)(src + i + 4);
        short8 o;
        o[0]=f2bf(a.x); o[1]=f2bf(a.y); o[2]=f2bf(a.z); o[3]=f2bf(a.w);
        o[4]=f2bf(b.x); o[5]=f2bf(b.y); o[6]=f2bf(b.z); o[7]=f2bf(b.w);
        *(short8*)(dst + i) = o;
    }
}

// ---------- prep: tiled W[k][n] -> Wt[n][k] bf16, 4 weights ----------
__global__ __launch_bounds__(256) void castWT4_kernel(
        const float* __restrict__ W0, const float* __restrict__ W1,
        const float* __restrict__ W2, const float* __restrict__ W3,
        short* __restrict__ T0, short* __restrict__ T1,
        short* __restrict__ T2, short* __restrict__ T3) {
    __shared__ short tile[64 * 68];
    int w = blockIdx.z;
    const float* W = w==0 ? W0 : w==1 ? W1 : w==2 ? W2 : W3;
    short* T = w==0 ? T0 : w==1 ? T1 : w==2 ? T2 : T3;
    int ti = blockIdx.x, tj = blockIdx.y;
    int tid = threadIdx.x;
    #pragma unroll
    for (int p = 0; p < 4; ++p) {
        int idx = tid + p * 256;
        int kl = idx >> 4, c4 = idx & 15;
        float4 f = *(const float4*)(W + (size_t)(tj*64 + kl) * DMODEL + ti*64 + c4*4);
        short4v s; s[0]=f2bf(f.x); s[1]=f2bf(f.y); s[2]=f2bf(f.z); s[3]=f2bf(f.w);
        *(short4v*)(tile + kl*68 + c4*4) = s;
    }
    __syncthreads();
    #pragma unroll
    for (int p = 0; p < 4; ++p) {
        int idx = tid + p * 256;
        int nl = idx >> 4, kseg = idx & 15;
        short4v s;
        #pragma unroll
        for (int i = 0; i < 4; ++i) s[i] = tile[(kseg*4 + i)*68 + nl];
        *(short4v*)(T + (size_t)(ti*64 + nl) * DMODEL + tj*64 + kseg*4) = s;
    }
}

// ---------- prep: mask -> MFMA-lane-ordered bitmask words ----------
// word index = ((((b*64+qg)*32 + w64)*2 + rg)*4 + r)*4 + kg  (qg = 32-query group)
// bit l (= 16*lg + lm) = mask[qg*32 + rg*16 + lg*4 + r][w64*64 + kg*16 + lm]
__global__ __launch_bounds__(256) void maskpack_kernel(
        const int* __restrict__ mask, unsigned long long* __restrict__ mp) {
    int gw = blockIdx.x * 4 + (threadIdx.x >> 6);
    int lane = threadIdx.x & 63;
    int r   = gw & 3;
    int rg  = (gw >> 2) & 1;
    int w64 = (gw >> 3) & 31;
    int qg  = (gw >> 8) & 63;
    int b   = gw >> 14;
    int row = qg * 32 + rg * 16 + (lane >> 4) * 4 + r;
    const int* src = mask + ((size_t)b * SEQ + row) * SEQ + w64 * 64 + (lane & 15);
    unsigned long long w0 = __ballot(src[0]  != 0);
    unsigned long long w1 = __ballot(src[16] != 0);
    unsigned long long w2 = __ballot(src[32] != 0);
    unsigned long long w3 = __ballot(src[48] != 0);
    if (lane == 0) {
        unsigned long long* d = mp + (size_t)gw * 4;
        d[0] = w0; d[1] = w1; d[2] = w2; d[3] = w3;
    }
}

// ---------- fused QKV projection: 128x128 tiles, DMA-swizzled W, V^T output ----------
__global__ __launch_bounds__(256, 4) void proj_qkv_kernel(
        const short* __restrict__ qn, const short* __restrict__ kb,
        const short* __restrict__ vb,
        const short* __restrict__ Wqt, const short* __restrict__ Wkt,
        const short* __restrict__ Wvt,
        short* __restrict__ qhp, short* __restrict__ khp, short* __restrict__ vtp) {
    __shared__ __align__(16) short Wl[2 * 8192];     // 32 KB
    int tid = threadIdx.x, wave = tid >> 6, lane = tid & 63;
    int lm = lane & 15, lg = lane >> 4;
    int which = blockIdx.y >> 2;
    int CB0 = (blockIdx.y & 3) * 128;
    const short* A  = which==0 ? qn  : which==1 ? kb  : vb;
    const short* Wt = which==0 ? Wqt : which==1 ? Wkt : Wvt;
    // Q gets 1/sqrt(64) * log2(e) folded in (attention uses exp2)
    float scale = which==0 ? 0.18033688f : 1.0f;

    int RBw = blockIdx.x * 128 + wave * 32;
    const short* Arow0 = A + (size_t)(RBw + lm) * DMODEL;
    const short* Arow1 = A + (size_t)(RBw + 16 + lm) * DMODEL;
    const short* W0 = Wt + (size_t)CB0 * DMODEL;

    short8 a[2][2];
    a[0][0] = *(const short8*)(Arow0 + lg * 8);
    a[0][1] = *(const short8*)(Arow0 + 32 + lg * 8);
    a[1][0] = *(const short8*)(Arow1 + lg * 8);
    a[1][1] = *(const short8*)(Arow1 + 32 + lg * 8);
    stage128x64(W0, DMODEL, Wl, tid);
    __syncthreads();

    f32x4 acc[2][8] = {};
    for (int kk = 0; kk < DMODEL; kk += 64) {
        int cur = (kk >> 6) & 1;
        bool more = (kk + 64) < DMODEL;
        short8 an[2][2];
        if (more) {
            stage128x64(W0 + kk + 64, DMODEL, Wl + (cur ^ 1) * 8192, tid);
            an[0][0] = *(const short8*)(Arow0 + kk + 64 + lg * 8);
            an[0][1] = *(const short8*)(Arow0 + kk + 96 + lg * 8);
            an[1][0] = *(const short8*)(Arow1 + kk + 64 + lg * 8);
            an[1][1] = *(const short8*)(Arow1 + kk + 96 + lg * 8);
        }
        const short* Wc = Wl + cur * 8192;
        #pragma unroll
        for (int cg = 0; cg < 8; ++cg) {
            short8 b0 = trd(Wc, cg*16 + lm, lg);
            short8 b1 = trd(Wc, cg*16 + lm, lg + 4);
            #pragma unroll
            for (int rg = 0; rg < 2; ++rg) {
                acc[rg][cg] = MFMA16(a[rg][0], b0, acc[rg][cg]);
                acc[rg][cg] = MFMA16(a[rg][1], b1, acc[rg][cg]);
            }
        }
        if (more) {
            #pragma unroll
            for (int rg = 0; rg < 2; ++rg) { a[rg][0] = an[rg][0]; a[rg][1] = an[rg][1]; }
        }
        __syncthreads();
    }

    if (which < 2) {
        short* outh = which==0 ? qhp : khp;
        #pragma unroll
        for (int rg = 0; rg < 2; ++rg) {
            #pragma unroll
            for (int cg = 0; cg < 8; ++cg) {
                int n = CB0 + cg * 16 + lm;
                int h = n >> 6, d = n & 63;
                #pragma unroll
                for (int r = 0; r < 4; ++r) {
                    int m = RBw + rg * 16 + lg * 4 + r;
                    int bb = m >> 11, s = m & 2047;
                    outh[(size_t)(bb * NHEAD + h) * HSTRIDE + (size_t)s * DQKV + d] =
                        f2bf(acc[rg][cg][r] * scale);
                }
            }
        }
    } else {
        // V output transposed: vt[b][h][d][s], packed 4-wide along s
        int bb = RBw >> 11;
        #pragma unroll
        for (int rg = 0; rg < 2; ++rg) {
            int s0 = (RBw + rg * 16 + lg * 4) & 2047;
            #pragma unroll
            for (int cg = 0; cg < 8; ++cg) {
                int n = CB0 + cg * 16 + lm;
                int h = n >> 6, d = n & 63;
                short4v pk;
                #pragma unroll
                for (int r = 0; r < 4; ++r) pk[r] = f2bf(acc[rg][cg][r]);
                *(short4v*)(vtp + (size_t)(bb * NHEAD + h) * HSTRIDE
                            + (size_t)d * SEQ + s0) = pk;
            }
        }
    }
}

// ---------- flash attention: 64 q/block (16 q/wave), DMA-swizzled dbuf ----------
// LDS (shorts): K at 0 (+cur*4096), V at 8192 (+cur*4096), P at 16384 (+wave*1024)
__global__ __launch_bounds__(256, 4) void attn_kernel(
        const short* __restrict__ qh, const short* __restrict__ kh,
        const short* __restrict__ vt, const unsigned long long* __restrict__ mpack,
        short* __restrict__ oh) {
    __shared__ __align__(16) short lds[20480];   // 40960 B -> 4 blocks/CU
    int tid = threadIdx.x, wave = tid >> 6, lane = tid & 63;
    int lm = lane & 15, lg = lane >> 4;
    int qt = blockIdx.x, bh = blockIdx.y, b = bh >> 3;
    int qbase = qt * 64 + wave * 16;
    short* Pw = lds + 16384 + wave * 1024;

    const short* Kbase = kh + (size_t)bh * HSTRIDE;
    const short* Vtb   = vt + (size_t)bh * HSTRIDE;

    const short8* Qrow = (const short8*)(qh + (size_t)bh * HSTRIDE
                          + (size_t)(qbase + lm) * DQKV);
    short8 aq0 = Qrow[lg];
    short8 aq1 = Qrow[lg + 4];

    // wave-uniform mask base (scalar loads): qg = 32-query group, rg = half
    int mblk = __builtin_amdgcn_readfirstlane(
        ((b * 64 + qt * 2 + (wave >> 1)) << 10) + ((wave & 1) << 4));
    const unsigned long long* mbase = mpack + mblk;

    const short one = (short)0x3F80;   // bf16 1.0
    short8 ones = {one, one, one, one, one, one, one, one};

    f32x4 o[4] = {};
    f32x4 ox{};

    // prologue: stage tile 0
    stage64x64(Kbase, DQKV, lds, tid);
    stage64x64(Vtb,   SEQ,  lds + 8192, tid);
    __syncthreads();

    for (int kt = 0; kt < SEQ; kt += 64) {
        int cur = (kt >> 6) & 1;
        if (kt + 64 < SEQ) {
            int nxt = cur ^ 1;
            stage64x64(Kbase + (size_t)(kt + 64) * DQKV, DQKV, lds + nxt * 4096, tid);
            stage64x64(Vtb + kt + 64, SEQ, lds + 8192 + nxt * 4096, tid);
        }
        const short* Kc = lds + cur * 4096;
        const short* Vc = lds + 8192 + cur * 4096;

        // ---- S = Q K^T ----
        f32x4 sk[4];
        #pragma unroll
        for (int kg = 0; kg < 4; ++kg) {
            short8 bk0 = trd(Kc, kg*16 + lm, lg);
            short8 bk1 = trd(Kc, kg*16 + lm, lg + 4);
            f32x4 z{};
            z = MFMA16(aq0, bk0, z);
            sk[kg] = MFMA16(aq1, bk1, z);
        }

        // ---- masked exp2 -> P (RNE bf16, swizzled LDS) ----
        const unsigned long long* mw = mbase + (kt >> 6) * 32;
        #pragma unroll
        for (int r = 0; r < 4; ++r) {
            int row = lg * 4 + r;
            short* pd = Pw + row * 64 + (lm & 7);
            #pragma unroll
            for (int kg = 0; kg < 4; ++kg) {
                unsigned long long mword = mw[r * 4 + kg];
                float e = __builtin_amdgcn_exp2f(sk[kg][r]);
                float pe;
                asm("v_cndmask_b32 %0, 0, %1, %2" : "=v"(pe) : "v"(e), "s"(mword));
                int c = (2 * kg + (lm >> 3)) ^ (row & 7);
                pd[c * 8] = f2bf(pe);
            }
        }

        // ---- P fragments (wave-private; compiler inserts lgkm wait) ----
        short8 ap0 = trd(Pw, lm, lg);
        short8 ap1 = trd(Pw, lm, lg + 4);

        // ---- O += P V ----
        #pragma unroll
        for (int dt = 0; dt < 4; ++dt) {
            short8 bv0 = trd(Vc, dt*16 + lm, lg);
            short8 bv1 = trd(Vc, dt*16 + lm, lg + 4);
            o[dt] = MFMA16(ap0, bv0, o[dt]);
            o[dt] = MFMA16(ap1, bv1, o[dt]);
        }
        // rowsum via constant all-ones B fragment (every output col = rowsum)
        ox = MFMA16(ap0, ones, ox);
        ox = MFMA16(ap1, ones, ox);
        __syncthreads();
    }

    // epilogue: normalize, store bf16
    short* ob = oh + (size_t)bh * HSTRIDE;
    float rinv[4];
    #pragma unroll
    for (int r = 0; r < 4; ++r) rinv[r] = __builtin_amdgcn_rcpf(ox[r]);
    #pragma unroll
    for (int dt = 0; dt < 4; ++dt) {
        #pragma unroll
        for (int r = 0; r < 4; ++r) {
            ob[(size_t)(qbase + lg * 4 + r) * DQKV + dt * 16 + lm] =
                f2bf(o[dt][r] * rinv[r]);
        }
    }
}

// ---------- output projection + residual: 64x64 tiles (16 rows/wave) ----------
__global__ __launch_bounds__(256, 4) void outproj_kernel(
        const short* __restrict__ Ah, const short* __restrict__ Wfct,
        const float* __restrict__ resid, float* __restrict__ out) {
    __shared__ __align__(16) short Wl[2 * 4096];    // 16 KB
    int tid = threadIdx.x, wave = tid >> 6, lane = tid & 63;
    int lm = lane & 15, lg = lane >> 4;
    int CB0 = blockIdx.y * 64;
    int RB = blockIdx.x * 64 + wave * 16;
    const short* W0 = Wfct + (size_t)CB0 * DMODEL;

    int m0 = RB + lm;
    size_t rb = (size_t)(m0 >> 11) * (NHEAD * HSTRIDE) + (size_t)(m0 & 2047) * DQKV;

    short8 a0 = *(const short8*)(Ah + rb + lg * 8);
    short8 a1 = *(const short8*)(Ah + rb + 32 + lg * 8);
    stage64x64(W0, DMODEL, Wl, tid);
    __syncthreads();

    f32x4 acc[4] = {};
    for (int kk = 0; kk < DMODEL; kk += 64) {
        int cur = (kk >> 6) & 1;
        bool more = (kk + 64) < DMODEL;
        short8 a0n, a1n;
        if (more) {
            stage64x64(W0 + kk + 64, DMODEL, Wl + (cur ^ 1) * 4096, tid);
            size_t hoff = (size_t)((kk >> 6) + 1) * HSTRIDE;
            a0n = *(const short8*)(Ah + rb + hoff + lg * 8);
            a1n = *(const short8*)(Ah + rb + hoff + 32 + lg * 8);
        }
        const short* Wc = Wl + cur * 4096;
        #pragma unroll
        for (int cg = 0; cg < 4; ++cg) {
            short8 b0 = trd(Wc, cg*16 + lm, lg);
            short8 b1 = trd(Wc, cg*16 + lm, lg + 4);
            acc[cg] = MFMA16(a0, b0, acc[cg]);
            acc[cg] = MFMA16(a1, b1, acc[cg]);
        }
        if (more) { a0 = a0n; a1 = a1n; }
        __syncthreads();
    }

    #pragma unroll
    for (int cg = 0; cg < 4; ++cg) {
        int n = CB0 + cg * 16 + lm;
        #pragma unroll
        for (int r = 0; r < 4; ++r) {
            int m = RB + lg * 4 + r;
            size_t idx = (size_t)m * DMODEL + n;
            out[idx] = acc[cg][r] + resid[idx];
        }
    }
}

// ---------- host launch ----------
extern "C" void kernel_launch(void* const* d_in, const int* in_sizes, int n_in,
                              void* d_out, int out_size, void* d_ws, size_t ws_size,
                              hipStream_t stream) {
    const float* q     = (const float*)d_in[0];
    const float* k     = (const float*)d_in[1];
    const float* v     = (const float*)d_in[2];
    const int*   mask  = (const int*)d_in[3];
    const float* Wq    = (const float*)d_in[4];
    const float* Wk    = (const float*)d_in[5];
    const float* Wv    = (const float*)d_in[6];
    const float* Wfc   = (const float*)d_in[7];
    const float* gamma = (const float*)d_in[8];
    const float* beta  = (const float*)d_in[9];
    float* out = (float*)d_out;

    char* ws = (char*)d_ws;
    const size_t SZ_ROWS = (size_t)ROWS * DMODEL * sizeof(short);   // 8 MB
    const size_t SZ_W    = (size_t)DMODEL * DMODEL * sizeof(short); // 512 KB
    short* qn   = (short*)(ws);
    short* kbf  = (short*)(ws + SZ_ROWS);
    short* vbf  = (short*)(ws + 2 * SZ_ROWS);
    short* Wqt  = (short*)(ws + 3 * SZ_ROWS);
    short* Wkt  = (short*)(ws + 3 * SZ_ROWS + SZ_W);
    short* Wvt  = (short*)(ws + 3 * SZ_ROWS + 2 * SZ_W);
    short* Wfct = (short*)(ws + 3 * SZ_ROWS + 3 * SZ_W);
    short* qhb  = (short*)(ws + 3 * SZ_ROWS + 4 * SZ_W);
    short* khb  = (short*)(ws + 4 * SZ_ROWS + 4 * SZ_W);
    short* vtb  = (short*)(ws + 5 * SZ_ROWS + 4 * SZ_W);
    unsigned long long* mpack = (unsigned long long*)(ws + 6 * SZ_ROWS + 4 * SZ_W); // 2 MB
    short* aout = qn;    // qn dead after proj

    prep_kernel<<<dim3(ROWS / 4, 3), 256, 0, stream>>>(q, k, v, gamma, beta, qn, kbf, vbf);
    castWT4_kernel<<<dim3(8, 8, 4), 256, 0, stream>>>(Wq, Wk, Wv, Wfc, Wqt, Wkt, Wvt, Wfct);
    maskpack_kernel<<<65536 / 4, 256, 0, stream>>>(mask, mpack);

    proj_qkv_kernel<<<dim3(ROWS / 128, 12), 256, 0, stream>>>(
        qn, kbf, vbf, Wqt, Wkt, Wvt, qhb, khb, vtb);

    attn_kernel<<<dim3(SEQ / 64, BH), 256, 0, stream>>>(qhb, khb, vtb, mpack, aout);

    outproj_kernel<<<dim3(ROWS / 64, DMODEL / 64), 256, 0, stream>>>(aout, Wfct, q, out);
}